// Round 8
// baseline (353.821 us; speedup 1.0000x reference)
//
#include <hip/hip_runtime.h>

// SparseMCFModel — output `flow` depends ONLY on demands, edge_row, edge_col.
// w_e = 1/deg(row_e) exactly (softmax over identical logits per segment) -> the
// GAT/GRU/decoder pipeline is dead code. Since w_e depends on row only:
//   flow_k[e] = V_k[row_e],  V_j[v] = (1/deg[v])*(dpos[v] + sum_{e:col=v} V_{j-1}[row_e])
//   V_0 = dpos/deg,  output = flow_10 = V_9[row_e].
// Per-edge payload collapses to {row} (4B). Per-iteration state V (80KB) is
// LDS-resident per block: gathers hit LDS, refill is one coalesced coherent
// read of V per block, stores are coalesced (contiguous node ownership).
//
// Validated protocol (r5-r7): zero-cache-op relaxed monotone barrier
// (__syncthreads drains vmcnt before s_barrier; all cross-block mutable data
// through agent-scope relaxed atomics = coherent point; lines written by
// st_coh are never cached stale because they are only plain-read AFTER the
// barrier and were never plain-read before).
// 256 blocks x 256 thr, 80KB LDS -> worst-case 2 blocks/CU packing still fits
// all 256 blocks resident => custom barrier cannot deadlock.

#define N_NODES 20000
#define N_EDGES 200000
#define FLOW_ITERS 10
#define NBLK 256
#define NTHR 256
#define NTOT (NBLK * NTHR)                 // 65536
#define EPT ((N_EDGES + NTOT - 1) / NTOT)  // 4 edges/thread (build + final)
#define NPB ((N_NODES + NBLK - 1) / NBLK)  // 79 owned nodes per block
#define CAP 32                             // padded CSC slots per node
#define OFL_MAX 4096
#define POISON_I ((int)0xAAAAAAAA)

__device__ __forceinline__ float ld_coh(const float* p) {
    return __hip_atomic_load(p, __ATOMIC_RELAXED, __HIP_MEMORY_SCOPE_AGENT);
}
__device__ __forceinline__ int ld_coh_i(const int* p) {
    return __hip_atomic_load(p, __ATOMIC_RELAXED, __HIP_MEMORY_SCOPE_AGENT);
}
__device__ __forceinline__ void st_coh(float* p, float v) {
    __hip_atomic_store(p, v, __ATOMIC_RELAXED, __HIP_MEMORY_SCOPE_AGENT);
}
__device__ __forceinline__ void st_coh_i(int* p, int v) {
    __hip_atomic_store(p, v, __ATOMIC_RELAXED, __HIP_MEMORY_SCOPE_AGENT);
}

__device__ __forceinline__ void gbar(int* cnt, int target) {
    __syncthreads();
    if (threadIdx.x == 0) {
        __hip_atomic_fetch_add(cnt, 1, __ATOMIC_RELAXED, __HIP_MEMORY_SCOPE_AGENT);
        while (__hip_atomic_load(cnt, __ATOMIC_RELAXED, __HIP_MEMORY_SCOPE_AGENT) < target)
            __builtin_amdgcn_s_sleep(4);
    }
    __syncthreads();
}

__global__ __launch_bounds__(NTHR)
void mcf_fused(const float* __restrict__ demands,
               const int* __restrict__ edge_row,
               const int* __restrict__ edge_col,
               float* __restrict__ out,
               int* __restrict__ deg,       // [N] out-degree
               int* __restrict__ fill,      // [N] in-degree cursors
               float* __restrict__ Vglob,   // [N]
               int* __restrict__ csc_row,   // [N*CAP], v-major: [v*CAP + k]
               int* __restrict__ ofl_cnt,   // [1]
               int* __restrict__ ofl_v,     // [OFL_MAX]
               int* __restrict__ ofl_row,   // [OFL_MAX]
               int* __restrict__ barcnt)    // [1], CAS-initialized from poison
{
    const int tid = blockIdx.x * NTHR + threadIdx.x;
    int bar = 0;

    __shared__ float ldsV[N_NODES + 1];    // +1 = zero sentinel for dummy slots

    if (threadIdx.x == 0) atomicCAS(barcnt, POISON_I, 0);

    // ---- Phase A: zero deg + fill ----
    for (int v = tid; v < N_NODES; v += NTOT) {
        st_coh_i(&deg[v], 0);
        st_coh_i(&fill[v], 0);
    }
    if (tid == 0) st_coh_i(ofl_cnt, 0);
    gbar(barcnt, NBLK * (++bar));

    // ---- Phase B: deg histogram + fill cursors + CSC placement (one pass) ----
    int rowr[EPT];
    #pragma unroll
    for (int i = 0; i < EPT; ++i) {
        int e = tid + i * NTOT;
        rowr[i] = 0;
        if (e < N_EDGES) {
            int r = edge_row[e], c = edge_col[e];
            rowr[i] = r;
            __hip_atomic_fetch_add(&deg[r], 1, __ATOMIC_RELAXED, __HIP_MEMORY_SCOPE_AGENT);
            int idx = __hip_atomic_fetch_add(&fill[c], 1,
                                             __ATOMIC_RELAXED, __HIP_MEMORY_SCOPE_AGENT);
            if (idx < CAP) {
                st_coh_i(&csc_row[c * CAP + idx], r);
            } else {
                int o = __hip_atomic_fetch_add(ofl_cnt, 1,
                                               __ATOMIC_RELAXED, __HIP_MEMORY_SCOPE_AGENT);
                if (o < OFL_MAX) { st_coh_i(&ofl_v[o], c); st_coh_i(&ofl_row[o], r); }
            }
        }
    }
    gbar(barcnt, NBLK * (++bar));

    // ---- Phase C: owner setup (contiguous ownership, coalesced reads) ----
    const int t = threadIdx.x;
    const int v = blockIdx.x * NPB + t;
    const bool active = (t < NPB) && (v < N_NODES);
    float dposv = 0.0f, inv_degv = 0.0f;
    int   cnt = 0, ocnt = 0;
    int   er[CAP];
    if (active) {
        dposv    = fmaxf(demands[v], 0.0f);
        int dv   = ld_coh_i(&deg[v]);
        inv_degv = (dv > 0) ? (1.0f / (float)dv) : 0.0f;  // V[v] unread if deg==0
        cnt      = min(ld_coh_i(&fill[v]), CAP);
        ocnt     = ld_coh_i(ofl_cnt);                     // expected 0
        #pragma unroll
        for (int k = 0; k < CAP; ++k) {
            int r = csc_row[v * CAP + k];   // plain, contiguous per thread
            er[k] = (k < cnt) ? r : N_NODES;  // dummy -> LDS zero sentinel
        }
    }

    // ---- V_0 = dpos/deg into LDS (coalesced; deg fresh after Phase-B bar) ----
    for (int i = threadIdx.x; i < N_NODES; i += NTHR) {
        int dv = ld_coh_i(&deg[i]);
        ldsV[i] = (dv > 0) ? (fmaxf(demands[i], 0.0f) / (float)dv) : 0.0f;
    }
    if (threadIdx.x == 0) ldsV[N_NODES] = 0.0f;   // sentinel, set once
    __syncthreads();

    // ---- 9 iterations: LDS gather -> coalesced coherent store -> refill ----
    #pragma unroll 1
    for (int k = 1; k <= FLOW_ITERS - 1; ++k) {
        if (active) {
            float acc = dposv;
            #pragma unroll
            for (int s = 0; s < CAP; ++s) acc += ldsV[er[s]];
            if (ocnt > 0) {                        // exactness fallback, ~never
                for (int o = 0; o < ocnt && o < OFL_MAX; ++o)
                    if (ld_coh_i(&ofl_v[o]) == v)
                        acc += ldsV[ld_coh_i(&ofl_row[o])];
            }
            st_coh(&Vglob[v], acc * inv_degv);     // coalesced across lanes
        }
        gbar(barcnt, NBLK * (++bar));
        for (int i = threadIdx.x; i < N_NODES; i += NTHR)
            ldsV[i] = ld_coh(&Vglob[i]);           // coalesced coherent refill
        __syncthreads();
    }

    // ---- out[e] = V_9[row_e], gathered from LDS; coalesced stores ----
    #pragma unroll
    for (int i = 0; i < EPT; ++i) {
        int e = tid + i * NTOT;
        if (e < N_EDGES) out[e] = ldsV[rowr[i]];
    }
}

extern "C" void kernel_launch(void* const* d_in, const int* in_sizes, int n_in,
                              void* d_out, int out_size, void* d_ws, size_t ws_size,
                              hipStream_t stream) {
    const float* demands  = (const float*)d_in[1];
    const int*   edge_row = (const int*)d_in[2];
    const int*   edge_col = (const int*)d_in[3];
    float*       out      = (float*)d_out;

    char* ws = (char*)d_ws;
    auto take = [&](size_t bytes) {
        void* p = (void*)ws;
        ws += (bytes + 127) & ~size_t(127);
        return p;
    };
    int*   deg     = (int*)  take(N_NODES * 4);
    int*   fill    = (int*)  take(N_NODES * 4);
    float* Vglob   = (float*)take(N_NODES * 4);
    int*   csc_row = (int*)  take((size_t)N_NODES * CAP * 4);
    int*   ofl_cnt = (int*)  take(4);
    int*   ofl_v   = (int*)  take(OFL_MAX * 4);
    int*   ofl_row = (int*)  take(OFL_MAX * 4);
    int*   barcnt  = (int*)  take(4);

    mcf_fused<<<NBLK, NTHR, 0, stream>>>(demands, edge_row, edge_col, out,
                                         deg, fill, Vglob, csc_row,
                                         ofl_cnt, ofl_v, ofl_row, barcnt);
}

// Round 9
// 145.223 us; speedup vs baseline: 2.4364x; 2.4364x over previous
//
#include <hip/hip_runtime.h>

// SparseMCFModel — output `flow` depends ONLY on demands, edge_row, edge_col.
// w_e = 1/deg(row_e) exactly (softmax over identical logits per segment) -> the
// GAT/GRU/decoder pipeline is dead code. Since w depends on row only:
//   flow_j[e] = V_j[row_e],
//   V_1[v] = relu(d[v])/deg[v],
//   V_j[v] = (relu(d[v]) + sum_{e:col=v} V_{j-1}[row_e]) / deg[v],  j=2..10
//   out[e] = V_10[row_e].
//
// Round-8 lesson: broadcasting V into every block's LDS (20 MB/iter agent-scope
// reads, 4 waves/CU) costs ~30 us/iter — 10x worse than direct random gathers
// (~0.8 MB/iter). This round: r7 topology (direct coherent gathers) + r8's
// row-only payload + ownership that is balanced AND coalesced:
//   block b owns nodes [157b, 157b+157) (every block equal work),
//   CSC stored pre-permuted by owner slot -> reg-cache reads lane-consecutive.
// Barrier: zero-cache-op relaxed monotone counter (validated r6-r8).

#define N_NODES 20000
#define N_EDGES 200000
#define FLOW_ITERS 10
#define NBLK 128
#define NTHR 512
#define NTOT (NBLK * NTHR)                 // 65536
#define EPT ((N_EDGES + NTOT - 1) / NTOT)  // 4 edges/thread (build + final)
#define NPB 157                            // nodes per block (128*157 = 20096)
#define CAP 32                             // padded in-edge slots per node
#define SLOTS NTOT                         // padded slot space (bx*NTHR + tx)
#define OFL_MAX 4096
#define POISON_I ((int)0xAAAAAAAA)

__device__ __forceinline__ float ld_coh(const float* p) {
    return __hip_atomic_load(p, __ATOMIC_RELAXED, __HIP_MEMORY_SCOPE_AGENT);
}
__device__ __forceinline__ int ld_coh_i(const int* p) {
    return __hip_atomic_load(p, __ATOMIC_RELAXED, __HIP_MEMORY_SCOPE_AGENT);
}
__device__ __forceinline__ void st_coh(float* p, float v) {
    __hip_atomic_store(p, v, __ATOMIC_RELAXED, __HIP_MEMORY_SCOPE_AGENT);
}
__device__ __forceinline__ void st_coh_i(int* p, int v) {
    __hip_atomic_store(p, v, __ATOMIC_RELAXED, __HIP_MEMORY_SCOPE_AGENT);
}

// Zero-cache-op monotone barrier (sound: __syncthreads drains vmcnt per wave
// before s_barrier, so coherent-point writes are globally visible before the
// relaxed arrive; all post-barrier cross-block reads use coherent-point ops or
// touch lines that were never cached stale).
__device__ __forceinline__ void gbar(int* cnt, int target) {
    __syncthreads();
    if (threadIdx.x == 0) {
        __hip_atomic_fetch_add(cnt, 1, __ATOMIC_RELAXED, __HIP_MEMORY_SCOPE_AGENT);
        while (__hip_atomic_load(cnt, __ATOMIC_RELAXED, __HIP_MEMORY_SCOPE_AGENT) < target)
            __builtin_amdgcn_s_sleep(4);
    }
    __syncthreads();
}

__global__ __launch_bounds__(NTHR)
void mcf_fused(const float* __restrict__ demands,
               const int* __restrict__ edge_row,
               const int* __restrict__ edge_col,
               float* __restrict__ out,
               int* __restrict__ deg,       // [N] out-degree
               int* __restrict__ fill,      // [N] in-edge cursors
               float* __restrict__ V0,      // [N+1] (+ sentinel 0)
               float* __restrict__ V1b,     // [N+1] (+ sentinel 0)
               int* __restrict__ pcsc,      // [CAP*SLOTS], [k*SLOTS + slot(v)]
               int* __restrict__ ofl_cnt,   // [1]
               int* __restrict__ ofl_v,     // [OFL_MAX]
               int* __restrict__ ofl_row,   // [OFL_MAX]
               int* __restrict__ barcnt)    // [1], CAS-initialized from poison
{
    const int tid = blockIdx.x * NTHR + threadIdx.x;
    int bar = 0;

    if (threadIdx.x == 0) atomicCAS(barcnt, POISON_I, 0);

    // ---- Phase A: zero deg/fill, sentinels, ofl_cnt ----
    for (int v = tid; v < N_NODES; v += NTOT) {
        st_coh_i(&deg[v], 0);
        st_coh_i(&fill[v], 0);
    }
    if (tid == 0) {
        st_coh_i(ofl_cnt, 0);
        st_coh(&V0[N_NODES], 0.0f);    // sentinel for padded slots
        st_coh(&V1b[N_NODES], 0.0f);   // never overwritten afterwards
    }
    gbar(barcnt, NBLK * (++bar));

    // ---- Phase B: deg histogram + slot-permuted CSC placement (one pass) ----
    int rowr[EPT];
    #pragma unroll
    for (int i = 0; i < EPT; ++i) {
        int e = tid + i * NTOT;
        rowr[i] = N_NODES;             // sentinel for inactive
        if (e < N_EDGES) {
            int r = edge_row[e], c = edge_col[e];
            rowr[i] = r;
            __hip_atomic_fetch_add(&deg[r], 1, __ATOMIC_RELAXED, __HIP_MEMORY_SCOPE_AGENT);
            int idx = __hip_atomic_fetch_add(&fill[c], 1,
                                             __ATOMIC_RELAXED, __HIP_MEMORY_SCOPE_AGENT);
            int slot = (c / NPB) * NTHR + (c % NPB);   // owner (block, thread)
            if (idx < CAP) {
                st_coh_i(&pcsc[idx * SLOTS + slot], r);
            } else {
                int o = __hip_atomic_fetch_add(ofl_cnt, 1,
                                               __ATOMIC_RELAXED, __HIP_MEMORY_SCOPE_AGENT);
                if (o < OFL_MAX) { st_coh_i(&ofl_v[o], c); st_coh_i(&ofl_row[o], r); }
            }
        }
    }
    gbar(barcnt, NBLK * (++bar));

    // ---- Phase C: owner setup (coalesced pcsc reads) + V_1 store ----
    const int tx = threadIdx.x;
    const int v  = blockIdx.x * NPB + tx;
    const bool active = (tx < NPB) && (v < N_NODES);
    float dposv = 0.0f, invd = 0.0f;
    int   cnt = 0, ocnt = 0;
    int   er[CAP];
    if (active) {
        dposv  = fmaxf(demands[v], 0.0f);
        int dv = ld_coh_i(&deg[v]);
        invd   = (dv > 0) ? (1.0f / (float)dv) : 0.0f;   // V[v] unread if deg==0
        cnt    = min(ld_coh_i(&fill[v]), CAP);
        ocnt   = ld_coh_i(ofl_cnt);                      // expected 0
        const int slot = blockIdx.x * NTHR + tx;         // lane-consecutive
        #pragma unroll
        for (int k = 0; k < CAP; ++k) {
            int r = pcsc[k * SLOTS + slot];   // plain, coalesced; lines never
            er[k] = (k < cnt) ? r : N_NODES;  // cached stale (written via st_coh)
        }
        st_coh(&V0[v], dposv * invd);         // V_1, coalesced store
    }
    gbar(barcnt, NBLK * (++bar));

    // ---- 9 iterations: CAP independent random coherent gathers per node ----
    #pragma unroll 1
    for (int j = 2; j <= FLOW_ITERS; ++j) {
        const float* Vp = (j & 1) ? V1b : V0;   // j even reads V0, writes V1b
        float*       Vn = (j & 1) ? V0 : V1b;
        if (active) {
            float sk[CAP];
            #pragma unroll
            for (int s = 0; s < CAP; ++s) sk[s] = ld_coh(&Vp[er[s]]);
            float acc = dposv;
            #pragma unroll
            for (int s = 0; s < CAP; ++s) acc += sk[s];
            if (ocnt > 0) {                     // exactness fallback, ~never
                for (int o = 0; o < ocnt && o < OFL_MAX; ++o)
                    if (ld_coh_i(&ofl_v[o]) == v)
                        acc += ld_coh(&Vp[ld_coh_i(&ofl_row[o])]);
            }
            st_coh(&Vn[v], acc * invd);         // coalesced
        }
        gbar(barcnt, NBLK * (++bar));
    }

    // ---- out[e] = V_10[row_e]  (j=10 wrote V1b); coalesced stores ----
    #pragma unroll
    for (int i = 0; i < EPT; ++i) {
        int e = tid + i * NTOT;
        if (e < N_EDGES) out[e] = ld_coh(&V1b[rowr[i]]);
    }
}

extern "C" void kernel_launch(void* const* d_in, const int* in_sizes, int n_in,
                              void* d_out, int out_size, void* d_ws, size_t ws_size,
                              hipStream_t stream) {
    const float* demands  = (const float*)d_in[1];
    const int*   edge_row = (const int*)d_in[2];
    const int*   edge_col = (const int*)d_in[3];
    float*       out      = (float*)d_out;

    char* ws = (char*)d_ws;
    auto take = [&](size_t bytes) {
        void* p = (void*)ws;
        ws += (bytes + 127) & ~size_t(127);
        return p;
    };
    int*   deg     = (int*)  take(N_NODES * 4);
    int*   fill    = (int*)  take(N_NODES * 4);
    float* V0      = (float*)take((N_NODES + 1) * 4);
    float* V1b     = (float*)take((N_NODES + 1) * 4);
    int*   pcsc    = (int*)  take((size_t)CAP * SLOTS * 4);
    int*   ofl_cnt = (int*)  take(4);
    int*   ofl_v   = (int*)  take(OFL_MAX * 4);
    int*   ofl_row = (int*)  take(OFL_MAX * 4);
    int*   barcnt  = (int*)  take(4);

    mcf_fused<<<NBLK, NTHR, 0, stream>>>(demands, edge_row, edge_col, out,
                                         deg, fill, V0, V1b, pcsc,
                                         ofl_cnt, ofl_v, ofl_row, barcnt);
}